// Round 15
// baseline (199.443 us; speedup 1.0000x reference)
//
#include <hip/hip_runtime.h>
#include <hip/hip_bf16.h>

#define ALPHA 0.01f
#define BETA  0.125f
#define NN    2048
#define NOBS  512
#define NB    16
#define TT    512
#define NCH   8      // t-chunks
#define CL    64     // chunk length

typedef __attribute__((ext_vector_type(8))) short short8;
typedef __attribute__((ext_vector_type(4))) float f32x4;

#define PP 0.86625f   /* 0.99*0.875 : obs diagonal */
#define QQ 0.99f      /* non-obs diagonal */

// ---- persistent device buffers ----
__device__ __align__(16) unsigned short g_X[NN * NN];          // X[j][k] = alpha*c_j*W[j][k]
__device__ __align__(16) unsigned short g_tchTb[TT][NB][NOBS]; // beta*teacher bf16, (t,b,k)
__device__ __align__(16) float          g_tchT[TT][NB][NOBS];  // beta*teacher fp32, (t,b,k)
__device__ __align__(16) unsigned short g_z0b[NB * NOBS];      // z0 (obs part) bf16
__device__ __align__(16) unsigned short g_VE[TT * NB * NN];    // (v_t E), (t,b,j)
__device__ __align__(16) unsigned short g_c1[NB * NN];
__device__ __align__(16) unsigned short g_c2a[NB * NN];
__device__ __align__(16) unsigned short g_c2b[NB * NN];
__device__ __align__(16) unsigned short g_c3aa[NB * NN];
__device__ __align__(16) unsigned short g_c3ab[NB * NN];
__device__ __align__(16) unsigned short g_c3ba[NB * NN];
__device__ __align__(16) unsigned short g_c3bb[NB * NN];
__device__ __align__(16) float g_wtab[2][TT][8];               // j-indep chains: w1,w2a,w2b,w3aa,w3ab,w3ba,w3bb,d^t
__device__ float g_lr[NCH][NB * NN], g_lh[NCH][NB * NN], g_lg[NCH][NB * NN];  // chunk locals
__device__ float g_sr[NCH][NB * NN], g_sh[NCH][NB * NN], g_sg[NCH][NB * NN];  // chunk starts

__device__ inline unsigned short f2bf(float f) {
    unsigned int x = __builtin_bit_cast(unsigned int, f);
    unsigned int r = (x + 0x7fffu + ((x >> 16) & 1u)) >> 16;   // RNE
    return (unsigned short)r;
}
__device__ inline float bf2f(unsigned short u) {
    unsigned int x = ((unsigned int)u) << 16;
    return __builtin_bit_cast(float, x);
}

// ---- setup: g_X[j][k] = alpha * c_j * W[j][k] ----
__global__ void build_x_kernel(const float* __restrict__ w) {
    int n4 = NN * NN / 4;
    const float4* w4 = reinterpret_cast<const float4*>(w);
    for (int i = blockIdx.x * blockDim.x + threadIdx.x; i < n4;
         i += gridDim.x * blockDim.x) {
        int row = (i * 4) >> 11;
        float sc = ALPHA * ((row < NOBS) ? 0.875f : 1.0f);
        float4 v = w4[i];
        ushort4 o;
        o.x = f2bf(v.x * sc); o.y = f2bf(v.y * sc); o.z = f2bf(v.z * sc); o.w = f2bf(v.w * sc);
        reinterpret_cast<ushort4*>(g_X)[i] = o;
    }
}

// ---- setup: teacher -> (t,b,k) beta-scaled, bf16 + fp32 ----
__global__ void tch_transpose_kernel(const float* __restrict__ tch) {
    __shared__ float tile[32][33];
    int b  = blockIdx.z;
    int n0 = blockIdx.x * 32;
    int t0 = blockIdx.y * 32;
    int j  = threadIdx.x & 31;
    int i4 = threadIdx.x >> 5;
#pragma unroll
    for (int r = 0; r < 4; ++r) {
        int i = r * 8 + i4;
        tile[i][j] = tch[((size_t)b * NOBS + (n0 + i)) * TT + (t0 + j)];
    }
    __syncthreads();
#pragma unroll
    for (int r = 0; r < 4; ++r) {
        int i = r * 8 + i4;
        float v = BETA * tile[j][i];
        g_tchTb[t0 + i][b][n0 + j] = f2bf(v);
        g_tchT[t0 + i][b][n0 + j]  = v;
    }
}

// ---- setup: z0 (obs) bf16 ----
__global__ void z0_init_kernel(const float* __restrict__ xt) {
    int idx = blockIdx.x * blockDim.x + threadIdx.x;
    if (idx >= NB * NOBS) return;
    g_z0b[idx] = f2bf(xt[(size_t)idx * TT]);
}

// ---- j-independent chain table: exact replica of the original ADV update order ----
__global__ void wtab_kernel() {
    int v = threadIdx.x;
    if (v >= 2) return;
    float d = v ? QQ : PP;
    float pw = 1.f, u1 = 0.f, u2 = 0.f;
    float y11 = 0.f, y12 = 0.f, y21 = 0.f, y22 = 0.f;
    float w1 = 0.f, w2a = 0.f, w2b = 0.f;
    float w3aa = 0.f, w3ab = 0.f, w3ba = 0.f, w3bb = 0.f;
    float dp = 1.f;
    for (int t = 1; t <= TT; ++t) {
        w3aa = d * w3aa + y11;  w3ab = d * w3ab + y12;
        w3ba = d * w3ba + y21;  w3bb = d * w3bb + y22;
        w2a  = d * w2a + u1;    w2b  = d * w2b + u2;
        w1   = d * w1 + pw;
        y11  = PP * y11 + u1;   y12 = QQ * y12 + u1;
        y21  = PP * y21 + u2;   y22 = QQ * y22 + u2;
        u1   = PP * u1 + pw;    u2  = QQ * u2 + pw;
        pw  *= PP;
        dp  *= d;
        float* o = g_wtab[v][t - 1];
        o[0] = w1; o[1] = w2a; o[2] = w2b; o[3] = w3aa;
        o[4] = w3ab; o[5] = w3ba; o[6] = w3bb; o[7] = dp;
    }
}

// ---- VE GEMM: g_VE[m][j] = sum_k tchTb[m][k] * X[j][k], BM=256 ----
__global__ __launch_bounds__(256)
void gemm_ve() {
    __shared__ __align__(16) unsigned short As[2][256 * 40];
    __shared__ __align__(16) unsigned short Bs[2][128 * 40];

    int tid = threadIdx.x;
    int wv  = tid >> 6;
    int l   = tid & 63;
    int ln  = l & 15;
    int kg  = l >> 4;
    int m0  = blockIdx.x * 256;
    int n0  = blockIdx.y * 128;

    int sr = tid >> 2;
    int sc = (tid & 3) * 8;

    const unsigned short* A = &g_tchTb[0][0][0];

    f32x4 acc[4][8] = {};
    short8 ra0, ra1, ra2, ra3, rb0, rb1;

#define STAGE_LOAD(ks) do {                                               \
        int ko = (ks) * 32 + sc;                                          \
        ra0 = *(const short8*)(A + (size_t)(m0 + sr) * 512 + ko);         \
        ra1 = *(const short8*)(A + (size_t)(m0 + 64 + sr) * 512 + ko);    \
        ra2 = *(const short8*)(A + (size_t)(m0 + 128 + sr) * 512 + ko);   \
        ra3 = *(const short8*)(A + (size_t)(m0 + 192 + sr) * 512 + ko);   \
        rb0 = *(const short8*)(g_X + (size_t)(n0 + sr) * NN + ko);        \
        rb1 = *(const short8*)(g_X + (size_t)(n0 + 64 + sr) * NN + ko);   \
    } while (0)
#define STAGE_WRITE(buf) do {                                             \
        *(short8*)&As[buf][sr * 40 + sc]         = ra0;                   \
        *(short8*)&As[buf][(64 + sr) * 40 + sc]  = ra1;                   \
        *(short8*)&As[buf][(128 + sr) * 40 + sc] = ra2;                   \
        *(short8*)&As[buf][(192 + sr) * 40 + sc] = ra3;                   \
        *(short8*)&Bs[buf][sr * 40 + sc]         = rb0;                   \
        *(short8*)&Bs[buf][(64 + sr) * 40 + sc]  = rb1;                   \
    } while (0)

    STAGE_LOAD(0);
    STAGE_WRITE(0);
    __syncthreads();

    for (int ks = 0; ks < 16; ++ks) {
        int buf = ks & 1;
        if (ks < 15) STAGE_LOAD(ks + 1);

        short8 af[4], bf[8];
#pragma unroll
        for (int f = 0; f < 4; ++f)
            af[f] = *(const short8*)&As[buf][(wv * 64 + f * 16 + ln) * 40 + kg * 8];
#pragma unroll
        for (int g2 = 0; g2 < 8; ++g2)
            bf[g2] = *(const short8*)&Bs[buf][(g2 * 16 + ln) * 40 + kg * 8];
#pragma unroll
        for (int fr = 0; fr < 4; ++fr)
#pragma unroll
            for (int fc = 0; fc < 8; ++fc)
                acc[fr][fc] = __builtin_amdgcn_mfma_f32_16x16x32_bf16(af[fr], bf[fc], acc[fr][fc], 0, 0, 0);

        if (ks < 15) STAGE_WRITE(buf ^ 1);
        __syncthreads();
    }
#undef STAGE_LOAD
#undef STAGE_WRITE

#pragma unroll
    for (int fr = 0; fr < 4; ++fr)
#pragma unroll
        for (int fc = 0; fc < 8; ++fc)
#pragma unroll
            for (int r = 0; r < 4; ++r) {
                int m = m0 + wv * 64 + fr * 16 + kg * 4 + r;
                int n = n0 + fc * 16 + ln;
                g_VE[(size_t)m * NN + n] = f2bf(acc[fr][fc][r]);
            }
}

// ---- small GEMM (M=16): C[b][j] = sum_k A[b][kofs+k] * X[j][kofs+k] ----
__global__ __launch_bounds__(256)
void gemm_small(int mode_base) {
    int mode = mode_base + blockIdx.z;
    const unsigned short* A; unsigned short* C; int lda, kofs, K;
    switch (mode) {
        case 0: A = g_z0b; C = g_c1;  lda = 512;  kofs = 0;   K = 512;  break;
        case 1: A = g_c1;  C = g_c2a; lda = 2048; kofs = 0;   K = 512;  break;
        case 2: A = g_c1;  C = g_c2b; lda = 2048; kofs = 512; K = 1536; break;
        case 3: A = g_c2a; C = g_c3aa; lda = 2048; kofs = 0;   K = 512;  break;
        case 4: A = g_c2a; C = g_c3ab; lda = 2048; kofs = 512; K = 1536; break;
        case 5: A = g_c2b; C = g_c3ba; lda = 2048; kofs = 0;   K = 512;  break;
        default: A = g_c2b; C = g_c3bb; lda = 2048; kofs = 512; K = 1536; break;
    }

    __shared__ float red[4][16][16];
    int tid = threadIdx.x;
    int wv  = tid >> 6;
    int l   = tid & 63;
    int ln  = l & 15;
    int kg  = l >> 4;
    int i0  = blockIdx.x * 16;
    int kq  = K / 4;
    int nit = kq / 32;

    f32x4 acc = {0.f, 0.f, 0.f, 0.f};
    for (int it = 0; it < nit; ++it) {
        int ko = kofs + wv * kq + it * 32 + kg * 8;
        short8 a = *(const short8*)(A + (size_t)ln * lda + ko);
        short8 b = *(const short8*)(g_X + (size_t)(i0 + ln) * NN + ko);
        acc = __builtin_amdgcn_mfma_f32_16x16x32_bf16(a, b, acc, 0, 0, 0);
    }
#pragma unroll
    for (int r = 0; r < 4; ++r) red[wv][kg * 4 + r][ln] = acc[r];
    __syncthreads();
    int b = tid >> 4, n = tid & 15;
    float s = red[0][b][n] + red[1][b][n] + red[2][b][n] + red[3][b][n];
    C[(size_t)b * NN + (i0 + n)] = f2bf(s);
}

// ---- pass 1: per-chunk local (r,H,G) scans, zero-init ----
__global__ __launch_bounds__(256)
void chunk_scan_kernel() {
    int tid = threadIdx.x;
    int b   = blockIdx.y * 2 + (tid >> 7);
    int j   = blockIdx.x * 128 + (tid & 127);
    int c   = blockIdx.z;
    bool obs = j < NOBS;
    float d  = obs ? PP : QQ;
    size_t cj = (size_t)b * NN + j;
    const unsigned short* vep = g_VE + cj;

    float r = 0.f, H = 0.f, G = 0.f;
    int t0 = c * CL;
#pragma unroll 8
    for (int i = 1; i <= CL; ++i) {
        int t = t0 + i;
        float vev = 0.f, vvc = 0.f;
        if (t < TT) {
            vev = bf2f(vep[(size_t)t * (NB * NN)]);
            if (obs) vvc = g_tchT[t][b][j];
        }
        G = d * G + H;
        H = PP * H + vev;
        r = d * r + vvc;
    }
    g_lr[c][cj] = r; g_lh[c][cj] = H; g_lg[c][cj] = G;
}

// ---- pass 2: combine chunk locals -> chunk start states (exact geometric coefs) ----
__global__ void combine_kernel() {
    int idx = blockIdx.x * blockDim.x + threadIdx.x;
    if (idx >= NB * NN) return;
    int j = idx & (NN - 1);
    bool obs = j < NOBS;
    float p2 = PP * PP, p4 = p2 * p2, p8 = p4 * p4, p16 = p8 * p8, p32 = p16 * p16, p64 = p32 * p32;
    float q2 = QQ * QQ, q4 = q2 * q2, q8 = q4 * q4, q16 = q8 * q8, q32 = q16 * q16, q64 = q32 * q32;
    float dL  = obs ? p64 : q64;
    float pL  = p64;
    float cGH = obs ? (64.0f * p64 / PP) : ((q64 - p64) / (QQ - PP));

    float r = 0.f, H = 0.f, G = 0.f;
#pragma unroll
    for (int c = 0; c < NCH; ++c) {
        g_sr[c][idx] = r; g_sh[c][idx] = H; g_sg[c][idx] = G;
        float rl = g_lr[c][idx], Hl = g_lh[c][idx], Gl = g_lg[c][idx];
        r = dL * r + rl;
        G = dL * G + cGH * H + Gl;
        H = pL * H + Hl;
    }
}

// ---- pass 3: per-chunk emission; col tau = (z_{tau+1} - v_{tau+1})*invc, col 0 = x0 ----
__global__ __launch_bounds__(256)
void emit_kernel(const float* __restrict__ xt, float* __restrict__ out) {
    int tid = threadIdx.x;
    int b   = blockIdx.y * 2 + (tid >> 7);
    int j   = blockIdx.x * 128 + (tid & 127);
    int c   = blockIdx.z;
    bool obs = j < NOBS;
    float d    = obs ? PP : QQ;
    float invc = obs ? (1.0f / 0.875f) : 1.0f;
    size_t cj = (size_t)b * NN + j;

    float c1v  = bf2f(g_c1[cj]);
    float c2av = bf2f(g_c2a[cj]),  c2bv = bf2f(g_c2b[cj]);
    float c3aav = bf2f(g_c3aa[cj]), c3abv = bf2f(g_c3ab[cj]);
    float c3bav = bf2f(g_c3ba[cj]), c3bbv = bf2f(g_c3bb[cj]);
    float z0j = obs ? xt[((size_t)b * NOBS + j) * TT] : 0.0f;

    float r = g_sr[c][cj], H = g_sh[c][cj], G = g_sg[c][cj];
    const unsigned short* vep = g_VE + cj;
    const float4* wt = (const float4*)g_wtab[obs ? 0 : 1][c * CL];  // entry (t-1)
    float* op = out + cj * TT + c * CL;
    int t0 = c * CL;

    for (int blk = 0; blk < CL / 16; ++blk) {
        float buf[16];
#pragma unroll
        for (int ii = 0; ii < 16; ++ii) {
            int i = blk * 16 + ii;
            int t = t0 + i + 1;
            float vev = 0.f, vvc = 0.f;
            if (t < TT) {
                vev = bf2f(vep[(size_t)t * (NB * NN)]);
                if (obs) vvc = g_tchT[t][b][j];
            }
            G = d * G + H;
            H = PP * H + vev;
            r = d * r + vvc;
            float4 wa = wt[i * 2];
            float4 wb = wt[i * 2 + 1];
            float zc = z0j * wb.w + wa.x * c1v + wa.y * c2av + wa.z * c2bv
                     + wa.w * c3aav + wb.x * c3abv + wb.y * c3bav + wb.z * c3bbv
                     + r + G;
            buf[ii] = (zc - vvc) * invc;
        }
        if (c == 0 && blk == 0) buf[0] = z0j;
        float4* o4 = (float4*)(op + blk * 16);
        o4[0] = make_float4(buf[0], buf[1], buf[2], buf[3]);
        o4[1] = make_float4(buf[4], buf[5], buf[6], buf[7]);
        o4[2] = make_float4(buf[8], buf[9], buf[10], buf[11]);
        o4[3] = make_float4(buf[12], buf[13], buf[14], buf[15]);
    }
}

extern "C" void kernel_launch(void* const* d_in, const int* in_sizes, int n_in,
                              void* d_out, int out_size, void* d_ws, size_t ws_size,
                              hipStream_t stream) {
    const float* xt = (const float*)d_in[0];   // (16, 512, 512)
    const float* w  = (const float*)d_in[1];   // (2048, 2048)
    float* out = (float*)d_out;                // (16, 2048, 512)

    hipLaunchKernelGGL(wtab_kernel, dim3(1), dim3(64), 0, stream);
    hipLaunchKernelGGL(build_x_kernel, dim3(1024), dim3(256), 0, stream, w);
    hipLaunchKernelGGL(tch_transpose_kernel, dim3(NOBS / 32, TT / 32, NB), dim3(256), 0, stream, xt);
    hipLaunchKernelGGL(z0_init_kernel, dim3(32), dim3(256), 0, stream, xt);
    hipLaunchKernelGGL(gemm_small, dim3(NN / 16, 1, 1), dim3(256), 0, stream, 0);      // c1
    hipLaunchKernelGGL(gemm_ve, dim3(TT * NB / 256, NN / 128), dim3(256), 0, stream);  // VE
    hipLaunchKernelGGL(gemm_small, dim3(NN / 16, 1, 2), dim3(256), 0, stream, 1);      // c2a,c2b
    hipLaunchKernelGGL(gemm_small, dim3(NN / 16, 1, 4), dim3(256), 0, stream, 3);      // c3aa..c3bb
    hipLaunchKernelGGL(chunk_scan_kernel, dim3(NN / 128, NB / 2, NCH), dim3(256), 0, stream);
    hipLaunchKernelGGL(combine_kernel, dim3(NB * NN / 256), dim3(256), 0, stream);
    hipLaunchKernelGGL(emit_kernel, dim3(NN / 128, NB / 2, NCH), dim3(256), 0, stream, xt, out);
}

// Round 16
// 142.669 us; speedup vs baseline: 1.3979x; 1.3979x over previous
//
#include <hip/hip_runtime.h>
#include <hip/hip_bf16.h>

#define ALPHA 0.01f
#define BETA  0.125f
#define NN    2048
#define NOBS  512
#define NB    16
#define TT    512

typedef __attribute__((ext_vector_type(8))) short short8;
typedef __attribute__((ext_vector_type(4))) float f32x4;

#define PP 0.86625f   /* 0.99*0.875 : obs diagonal */
#define QQ 0.99f      /* non-obs diagonal */

// ---- persistent device buffers ----
__device__ __align__(16) unsigned short g_X[NN * NN];          // X[j][k] = alpha*c_j*W[j][k]
__device__ __align__(16) unsigned short g_tchTb[TT][NB][NOBS]; // beta*teacher bf16, (t,b,k)
__device__ __align__(16) float          g_tchT[TT][NB][NOBS];  // beta*teacher fp32, (t,b,k)
__device__ __align__(16) unsigned short g_z0b[NB * NOBS];      // z0 (obs part) bf16
__device__ __align__(16) unsigned short g_VE[TT * NB * NN];    // (v_t E), (t,b,j)
__device__ __align__(16) unsigned short g_c1[NB * NN];
__device__ __align__(16) unsigned short g_c2a[NB * NN];
__device__ __align__(16) unsigned short g_c2b[NB * NN];
__device__ __align__(16) unsigned short g_c3aa[NB * NN];
__device__ __align__(16) unsigned short g_c3ab[NB * NN];
__device__ __align__(16) unsigned short g_c3ba[NB * NN];
__device__ __align__(16) unsigned short g_c3bb[NB * NN];

__device__ inline unsigned short f2bf(float f) {
    unsigned int x = __builtin_bit_cast(unsigned int, f);
    unsigned int r = (x + 0x7fffu + ((x >> 16) & 1u)) >> 16;   // RNE
    return (unsigned short)r;
}
__device__ inline float bf2f(unsigned short u) {
    unsigned int x = ((unsigned int)u) << 16;
    return __builtin_bit_cast(float, x);
}

// ---- setup: g_X[j][k] = alpha * c_j * W[j][k] ----
__global__ void build_x_kernel(const float* __restrict__ w) {
    int n4 = NN * NN / 4;
    const float4* w4 = reinterpret_cast<const float4*>(w);
    for (int i = blockIdx.x * blockDim.x + threadIdx.x; i < n4;
         i += gridDim.x * blockDim.x) {
        int row = (i * 4) >> 11;
        float sc = ALPHA * ((row < NOBS) ? 0.875f : 1.0f);
        float4 v = w4[i];
        ushort4 o;
        o.x = f2bf(v.x * sc); o.y = f2bf(v.y * sc); o.z = f2bf(v.z * sc); o.w = f2bf(v.w * sc);
        reinterpret_cast<ushort4*>(g_X)[i] = o;
    }
}

// ---- setup: teacher -> (t,b,k) beta-scaled, bf16 + fp32 ----
__global__ void tch_transpose_kernel(const float* __restrict__ tch) {
    __shared__ float tile[32][33];
    int b  = blockIdx.z;
    int n0 = blockIdx.x * 32;
    int t0 = blockIdx.y * 32;
    int j  = threadIdx.x & 31;
    int i4 = threadIdx.x >> 5;
#pragma unroll
    for (int r = 0; r < 4; ++r) {
        int i = r * 8 + i4;
        tile[i][j] = tch[((size_t)b * NOBS + (n0 + i)) * TT + (t0 + j)];
    }
    __syncthreads();
#pragma unroll
    for (int r = 0; r < 4; ++r) {
        int i = r * 8 + i4;
        float v = BETA * tile[j][i];
        g_tchTb[t0 + i][b][n0 + j] = f2bf(v);
        g_tchT[t0 + i][b][n0 + j]  = v;
    }
}

// ---- setup: z0 (obs) bf16 ----
__global__ void z0_init_kernel(const float* __restrict__ xt) {
    int idx = blockIdx.x * blockDim.x + threadIdx.x;
    if (idx >= NB * NOBS) return;
    g_z0b[idx] = f2bf(xt[(size_t)idx * TT]);
}

// ---- VE GEMM: g_VE[m][j] = sum_k tchTb[m][k] * X[j][k], BM=256 ----
__global__ __launch_bounds__(256)
void gemm_ve() {
    __shared__ __align__(16) unsigned short As[2][256 * 40];
    __shared__ __align__(16) unsigned short Bs[2][128 * 40];

    int tid = threadIdx.x;
    int wv  = tid >> 6;
    int l   = tid & 63;
    int ln  = l & 15;
    int kg  = l >> 4;
    int m0  = blockIdx.x * 256;
    int n0  = blockIdx.y * 128;

    int sr = tid >> 2;
    int sc = (tid & 3) * 8;

    const unsigned short* A = &g_tchTb[0][0][0];

    f32x4 acc[4][8] = {};
    short8 ra0, ra1, ra2, ra3, rb0, rb1;

#define STAGE_LOAD(ks) do {                                               \
        int ko = (ks) * 32 + sc;                                          \
        ra0 = *(const short8*)(A + (size_t)(m0 + sr) * 512 + ko);         \
        ra1 = *(const short8*)(A + (size_t)(m0 + 64 + sr) * 512 + ko);    \
        ra2 = *(const short8*)(A + (size_t)(m0 + 128 + sr) * 512 + ko);   \
        ra3 = *(const short8*)(A + (size_t)(m0 + 192 + sr) * 512 + ko);   \
        rb0 = *(const short8*)(g_X + (size_t)(n0 + sr) * NN + ko);        \
        rb1 = *(const short8*)(g_X + (size_t)(n0 + 64 + sr) * NN + ko);   \
    } while (0)
#define STAGE_WRITE(buf) do {                                             \
        *(short8*)&As[buf][sr * 40 + sc]         = ra0;                   \
        *(short8*)&As[buf][(64 + sr) * 40 + sc]  = ra1;                   \
        *(short8*)&As[buf][(128 + sr) * 40 + sc] = ra2;                   \
        *(short8*)&As[buf][(192 + sr) * 40 + sc] = ra3;                   \
        *(short8*)&Bs[buf][sr * 40 + sc]         = rb0;                   \
        *(short8*)&Bs[buf][(64 + sr) * 40 + sc]  = rb1;                   \
    } while (0)

    STAGE_LOAD(0);
    STAGE_WRITE(0);
    __syncthreads();

    for (int ks = 0; ks < 16; ++ks) {
        int buf = ks & 1;
        if (ks < 15) STAGE_LOAD(ks + 1);

        short8 af[4], bf[8];
#pragma unroll
        for (int f = 0; f < 4; ++f)
            af[f] = *(const short8*)&As[buf][(wv * 64 + f * 16 + ln) * 40 + kg * 8];
#pragma unroll
        for (int g2 = 0; g2 < 8; ++g2)
            bf[g2] = *(const short8*)&Bs[buf][(g2 * 16 + ln) * 40 + kg * 8];
#pragma unroll
        for (int fr = 0; fr < 4; ++fr)
#pragma unroll
            for (int fc = 0; fc < 8; ++fc)
                acc[fr][fc] = __builtin_amdgcn_mfma_f32_16x16x32_bf16(af[fr], bf[fc], acc[fr][fc], 0, 0, 0);

        if (ks < 15) STAGE_WRITE(buf ^ 1);
        __syncthreads();
    }
#undef STAGE_LOAD
#undef STAGE_WRITE

#pragma unroll
    for (int fr = 0; fr < 4; ++fr)
#pragma unroll
        for (int fc = 0; fc < 8; ++fc)
#pragma unroll
            for (int r = 0; r < 4; ++r) {
                int m = m0 + wv * 64 + fr * 16 + kg * 4 + r;
                int n = n0 + fc * 16 + ln;
                g_VE[(size_t)m * NN + n] = f2bf(acc[fr][fc][r]);
            }
}

// ---- small GEMM (M=16): C[b][j] = sum_k A[b][kofs+k] * X[j][kofs+k] ----
__global__ __launch_bounds__(256)
void gemm_small(int mode_base) {
    int mode = mode_base + blockIdx.z;
    const unsigned short* A; unsigned short* C; int lda, kofs, K;
    switch (mode) {
        case 0: A = g_z0b; C = g_c1;  lda = 512;  kofs = 0;   K = 512;  break;
        case 1: A = g_c1;  C = g_c2a; lda = 2048; kofs = 0;   K = 512;  break;
        case 2: A = g_c1;  C = g_c2b; lda = 2048; kofs = 512; K = 1536; break;
        case 3: A = g_c2a; C = g_c3aa; lda = 2048; kofs = 0;   K = 512;  break;
        case 4: A = g_c2a; C = g_c3ab; lda = 2048; kofs = 512; K = 1536; break;
        case 5: A = g_c2b; C = g_c3ba; lda = 2048; kofs = 0;   K = 512;  break;
        default: A = g_c2b; C = g_c3bb; lda = 2048; kofs = 512; K = 1536; break;
    }

    __shared__ float red[4][16][16];
    int tid = threadIdx.x;
    int wv  = tid >> 6;
    int l   = tid & 63;
    int ln  = l & 15;
    int kg  = l >> 4;
    int i0  = blockIdx.x * 16;
    int kq  = K / 4;
    int nit = kq / 32;

    f32x4 acc = {0.f, 0.f, 0.f, 0.f};
    for (int it = 0; it < nit; ++it) {
        int ko = kofs + wv * kq + it * 32 + kg * 8;
        short8 a = *(const short8*)(A + (size_t)ln * lda + ko);
        short8 b = *(const short8*)(g_X + (size_t)(i0 + ln) * NN + ko);
        acc = __builtin_amdgcn_mfma_f32_16x16x32_bf16(a, b, acc, 0, 0, 0);
    }
#pragma unroll
    for (int r = 0; r < 4; ++r) red[wv][kg * 4 + r][ln] = acc[r];
    __syncthreads();
    int b = tid >> 4, n = tid & 15;
    float s = red[0][b][n] + red[1][b][n] + red[2][b][n] + red[3][b][n];
    C[(size_t)b * NN + (i0 + n)] = f2bf(s);
}

// ---- final streaming pass (teacher m<=1, z0 m<=3), 256 blocks x 128 thr (all CUs) ----
// out col tau (tau>=1) = (z_{tau+1} - v_{tau+1})*invc ; col 0 = x0 ; v_512 = 0.
__global__ __launch_bounds__(128)
void stream_kernel(const float* __restrict__ xt, float* __restrict__ out) {
    int tid  = threadIdx.x;          // 0..127
    int b    = blockIdx.y;
    int j    = blockIdx.x * 128 + tid;
    bool obs = j < NOBS;
    float d    = obs ? PP : QQ;
    float invc = obs ? (1.0f / 0.875f) : 1.0f;

    size_t cj = (size_t)b * NN + j;
    float c1v  = bf2f(g_c1[cj]);
    float c2av = bf2f(g_c2a[cj]),  c2bv = bf2f(g_c2b[cj]);
    float c3aav = bf2f(g_c3aa[cj]), c3abv = bf2f(g_c3ab[cj]);
    float c3bav = bf2f(g_c3ba[cj]), c3bbv = bf2f(g_c3bb[cj]);
    float z0j = obs ? xt[((size_t)b * NOBS + j) * TT] : 0.0f;

    float pw = 1.0f;
    float u1 = 0.f, u2 = 0.f;
    float y11 = 0.f, y12 = 0.f, y21 = 0.f, y22 = 0.f;
    float w1 = 0.f, w2a = 0.f, w2b = 0.f;
    float w3aa = 0.f, w3ab = 0.f, w3ba = 0.f, w3bb = 0.f;
    float sd = z0j;
    float r = 0.f, H = 0.f, G = 0.f;

    float* op = out + cj * TT;
    const unsigned short* vep = g_VE + cj;

    float zc = 0.f, vvc = 0.f;

#define ADV(t_) do {                                                        \
        float vev = 0.f;                                                    \
        vvc = 0.f;                                                          \
        if ((t_) < TT) {                                                    \
            vev = bf2f(vep[(size_t)(t_) * (NB * NN)]);                      \
            if (obs) vvc = g_tchT[(t_)][b][j];                              \
        }                                                                   \
        w3aa = d * w3aa + y11;  w3ab = d * w3ab + y12;                      \
        w3ba = d * w3ba + y21;  w3bb = d * w3bb + y22;                      \
        w2a  = d * w2a + u1;    w2b  = d * w2b + u2;                        \
        w1   = d * w1 + pw;                                                 \
        G    = d * G + H;                                                   \
        H    = PP * H + vev;                                                \
        r    = d * r + vvc;                                                 \
        sd   = d * sd;                                                      \
        y11  = PP * y11 + u1;   y12 = QQ * y12 + u1;                        \
        y21  = PP * y21 + u2;   y22 = QQ * y22 + u2;                        \
        u1   = PP * u1 + pw;    u2  = QQ * u2 + pw;                         \
        pw  *= PP;                                                          \
        zc = sd + w1 * c1v + w2a * c2av + w2b * c2bv                        \
           + w3aa * c3aav + w3ab * c3abv + w3ba * c3bav + w3bb * c3bbv      \
           + r + G;                                                         \
    } while (0)

    float buf[16];

    buf[0] = z0j;
    ADV(1);
#pragma unroll
    for (int ti = 1; ti < 16; ++ti) {
        ADV(ti + 1);
        buf[ti] = (zc - vvc) * invc;
    }
    {
        float4* o4 = (float4*)op;
        o4[0] = make_float4(buf[0], buf[1], buf[2], buf[3]);
        o4[1] = make_float4(buf[4], buf[5], buf[6], buf[7]);
        o4[2] = make_float4(buf[8], buf[9], buf[10], buf[11]);
        o4[3] = make_float4(buf[12], buf[13], buf[14], buf[15]);
    }

    for (int tb = 16; tb < TT; tb += 16) {
#pragma unroll
        for (int ti = 0; ti < 16; ++ti) {
            ADV(tb + ti + 1);
            buf[ti] = (zc - vvc) * invc;
        }
        float4* o4 = (float4*)(op + tb);
        o4[0] = make_float4(buf[0], buf[1], buf[2], buf[3]);
        o4[1] = make_float4(buf[4], buf[5], buf[6], buf[7]);
        o4[2] = make_float4(buf[8], buf[9], buf[10], buf[11]);
        o4[3] = make_float4(buf[12], buf[13], buf[14], buf[15]);
    }
#undef ADV
}

extern "C" void kernel_launch(void* const* d_in, const int* in_sizes, int n_in,
                              void* d_out, int out_size, void* d_ws, size_t ws_size,
                              hipStream_t stream) {
    const float* xt = (const float*)d_in[0];   // (16, 512, 512)
    const float* w  = (const float*)d_in[1];   // (2048, 2048)
    float* out = (float*)d_out;                // (16, 2048, 512)

    hipLaunchKernelGGL(build_x_kernel, dim3(1024), dim3(256), 0, stream, w);
    hipLaunchKernelGGL(tch_transpose_kernel, dim3(NOBS / 32, TT / 32, NB), dim3(256), 0, stream, xt);
    hipLaunchKernelGGL(z0_init_kernel, dim3(32), dim3(256), 0, stream, xt);
    hipLaunchKernelGGL(gemm_small, dim3(NN / 16, 1, 1), dim3(256), 0, stream, 0);      // c1
    hipLaunchKernelGGL(gemm_ve, dim3(TT * NB / 256, NN / 128), dim3(256), 0, stream);  // VE
    hipLaunchKernelGGL(gemm_small, dim3(NN / 16, 1, 2), dim3(256), 0, stream, 1);      // c2a,c2b
    hipLaunchKernelGGL(gemm_small, dim3(NN / 16, 1, 4), dim3(256), 0, stream, 3);      // c3aa..c3bb
    hipLaunchKernelGGL(stream_kernel, dim3(NN / 128, NB), dim3(128), 0, stream, xt, out);
}

// Round 17
// 119.692 us; speedup vs baseline: 1.6663x; 1.1920x over previous
//
#include <hip/hip_runtime.h>
#include <hip/hip_bf16.h>

#define ALPHA 0.01f
#define BETA  0.125f
#define NN    2048
#define NOBS  512
#define NB    16
#define TT    512

typedef __attribute__((ext_vector_type(8))) short short8;
typedef __attribute__((ext_vector_type(4))) float f32x4;

#define PP 0.86625f   /* 0.99*0.875 : obs diagonal */
#define QQ 0.99f      /* non-obs diagonal */

// ---- persistent device buffers ----
__device__ __align__(16) unsigned short g_X[NN * NN];            // X[j][k] = alpha*c_j*W[j][k]
__device__ __align__(16) unsigned short g_tchTb[NB * TT * NOBS]; // beta*teacher bf16, (b,t,k)
__device__ __align__(16) unsigned short g_z0b[NB * NOBS];        // z0 (obs part) bf16
__device__ __align__(16) unsigned short g_VET[(size_t)NB * NN * TT]; // (v_t E) in (b,j,t), 32MB
__device__ __align__(16) unsigned short g_c1[NB * NN];
__device__ __align__(16) unsigned short g_c2a[NB * NN];
__device__ __align__(16) unsigned short g_c2b[NB * NN];
__device__ __align__(16) unsigned short g_c3aa[NB * NN];
__device__ __align__(16) unsigned short g_c3ab[NB * NN];
__device__ __align__(16) unsigned short g_c3ba[NB * NN];
__device__ __align__(16) unsigned short g_c3bb[NB * NN];

__device__ inline unsigned short f2bf(float f) {
    unsigned int x = __builtin_bit_cast(unsigned int, f);
    unsigned int r = (x + 0x7fffu + ((x >> 16) & 1u)) >> 16;   // RNE
    return (unsigned short)r;
}
__device__ inline float bf2f(unsigned short u) {
    unsigned int x = ((unsigned int)u) << 16;
    return __builtin_bit_cast(float, x);
}

// ---- setup: g_X[j][k] = alpha * c_j * W[j][k] ----
__global__ void build_x_kernel(const float* __restrict__ w) {
    int n4 = NN * NN / 4;
    const float4* w4 = reinterpret_cast<const float4*>(w);
    for (int i = blockIdx.x * blockDim.x + threadIdx.x; i < n4;
         i += gridDim.x * blockDim.x) {
        int row = (i * 4) >> 11;
        float sc = ALPHA * ((row < NOBS) ? 0.875f : 1.0f);
        float4 v = w4[i];
        ushort4 o;
        o.x = f2bf(v.x * sc); o.y = f2bf(v.y * sc); o.z = f2bf(v.z * sc); o.w = f2bf(v.w * sc);
        reinterpret_cast<ushort4*>(g_X)[i] = o;
    }
}

// ---- setup: teacher -> (b,t,k) beta-scaled bf16 ----
__global__ void tch_transpose_kernel(const float* __restrict__ tch) {
    __shared__ float tile[32][33];
    int b  = blockIdx.z;
    int n0 = blockIdx.x * 32;
    int t0 = blockIdx.y * 32;
    int j  = threadIdx.x & 31;
    int i4 = threadIdx.x >> 5;
#pragma unroll
    for (int r = 0; r < 4; ++r) {
        int i = r * 8 + i4;
        tile[i][j] = tch[((size_t)b * NOBS + (n0 + i)) * TT + (t0 + j)];
    }
    __syncthreads();
#pragma unroll
    for (int r = 0; r < 4; ++r) {
        int i = r * 8 + i4;
        g_tchTb[((size_t)b * TT + (t0 + i)) * NOBS + (n0 + j)] = f2bf(BETA * tile[j][i]);
    }
}

// ---- setup: z0 (obs) bf16 ----
__global__ void z0_init_kernel(const float* __restrict__ xt) {
    int idx = blockIdx.x * blockDim.x + threadIdx.x;
    if (idx >= NB * NOBS) return;
    g_z0b[idx] = f2bf(xt[(size_t)idx * TT]);
}

// ---- VE GEMM, transposed out: g_VET[b][j][t] = sum_k X[j][k] * tchTb[b][t][k] ----
__global__ __launch_bounds__(256)
void gemm_vet() {
    int bb = blockIdx.z;
    const unsigned short* B = g_tchTb + (size_t)bb * TT * NOBS;

    __shared__ __align__(16) unsigned short As[2][128 * 40];
    __shared__ __align__(16) unsigned short Bs[2][128 * 40];

    int tid = threadIdx.x;
    int wv  = tid >> 6;
    int l   = tid & 63;
    int wr  = wv >> 1;
    int wc  = wv & 1;
    int ln  = l & 15;
    int kg  = l >> 4;
    int m0  = blockIdx.x * 128;   // j tile
    int n0  = blockIdx.y * 128;   // t tile

    int sr = tid >> 2;
    int sc = (tid & 3) * 8;

    f32x4 acc[4][4] = {};
    short8 ra0, ra1, rb0, rb1;

#define STAGE_LOAD(ks) do {                                               \
        int ko = (ks) * 32 + sc;                                          \
        ra0 = *(const short8*)(g_X + (size_t)(m0 + sr) * NN + ko);        \
        ra1 = *(const short8*)(g_X + (size_t)(m0 + 64 + sr) * NN + ko);   \
        rb0 = *(const short8*)(B + (size_t)(n0 + sr) * NOBS + ko);        \
        rb1 = *(const short8*)(B + (size_t)(n0 + 64 + sr) * NOBS + ko);   \
    } while (0)
#define STAGE_WRITE(buf) do {                                             \
        *(short8*)&As[buf][sr * 40 + sc]        = ra0;                    \
        *(short8*)&As[buf][(64 + sr) * 40 + sc] = ra1;                    \
        *(short8*)&Bs[buf][sr * 40 + sc]        = rb0;                    \
        *(short8*)&Bs[buf][(64 + sr) * 40 + sc] = rb1;                    \
    } while (0)

    STAGE_LOAD(0);
    STAGE_WRITE(0);
    __syncthreads();

    for (int ks = 0; ks < 16; ++ks) {          // K = 512 (obs cols of X)
        int buf = ks & 1;
        if (ks < 15) STAGE_LOAD(ks + 1);

        short8 af[4], bf[4];
#pragma unroll
        for (int f = 0; f < 4; ++f) {
            af[f] = *(const short8*)&As[buf][(wr * 64 + f * 16 + ln) * 40 + kg * 8];
            bf[f] = *(const short8*)&Bs[buf][(wc * 64 + f * 16 + ln) * 40 + kg * 8];
        }
#pragma unroll
        for (int fr = 0; fr < 4; ++fr)
#pragma unroll
            for (int fc = 0; fc < 4; ++fc)
                acc[fr][fc] = __builtin_amdgcn_mfma_f32_16x16x32_bf16(af[fr], bf[fc], acc[fr][fc], 0, 0, 0);

        if (ks < 15) STAGE_WRITE(buf ^ 1);
        __syncthreads();
    }
#undef STAGE_LOAD
#undef STAGE_WRITE

#pragma unroll
    for (int fr = 0; fr < 4; ++fr)
#pragma unroll
        for (int fc = 0; fc < 4; ++fc)
#pragma unroll
            for (int r = 0; r < 4; ++r) {
                int m = m0 + wr * 64 + fr * 16 + kg * 4 + r;   // j
                int n = n0 + wc * 64 + fc * 16 + ln;           // t
                g_VET[((size_t)bb * NN + m) * TT + n] = f2bf(acc[fr][fc][r]);
            }
}

// ---- small GEMM (M=16): C[b][j] = sum_k A[b][kofs+k] * X[j][kofs+k] ----
__global__ __launch_bounds__(256)
void gemm_small(int mode_base) {
    int mode = mode_base + blockIdx.z;
    const unsigned short* A; unsigned short* C; int lda, kofs, K;
    switch (mode) {
        case 0: A = g_z0b; C = g_c1;  lda = 512;  kofs = 0;   K = 512;  break;
        case 1: A = g_c1;  C = g_c2a; lda = 2048; kofs = 0;   K = 512;  break;
        case 2: A = g_c1;  C = g_c2b; lda = 2048; kofs = 512; K = 1536; break;
        case 3: A = g_c2a; C = g_c3aa; lda = 2048; kofs = 0;   K = 512;  break;
        case 4: A = g_c2a; C = g_c3ab; lda = 2048; kofs = 512; K = 1536; break;
        case 5: A = g_c2b; C = g_c3ba; lda = 2048; kofs = 0;   K = 512;  break;
        default: A = g_c2b; C = g_c3bb; lda = 2048; kofs = 512; K = 1536; break;
    }

    __shared__ float red[4][16][16];
    int tid = threadIdx.x;
    int wv  = tid >> 6;
    int l   = tid & 63;
    int ln  = l & 15;
    int kg  = l >> 4;
    int i0  = blockIdx.x * 16;
    int kq  = K / 4;
    int nit = kq / 32;

    f32x4 acc = {0.f, 0.f, 0.f, 0.f};
    for (int it = 0; it < nit; ++it) {
        int ko = kofs + wv * kq + it * 32 + kg * 8;
        short8 a = *(const short8*)(A + (size_t)ln * lda + ko);
        short8 b = *(const short8*)(g_X + (size_t)(i0 + ln) * NN + ko);
        acc = __builtin_amdgcn_mfma_f32_16x16x32_bf16(a, b, acc, 0, 0, 0);
    }
#pragma unroll
    for (int r = 0; r < 4; ++r) red[wv][kg * 4 + r][ln] = acc[r];
    __syncthreads();
    int b = tid >> 4, n = tid & 15;
    float s = red[0][b][n] + red[1][b][n] + red[2][b][n] + red[3][b][n];
    C[(size_t)b * NN + (i0 + n)] = f2bf(s);
}

// ---- final streaming pass: t-contiguous loads + register double-buffer prefetch ----
// out col tau (tau>=1) = (z_{tau+1} - v_{tau+1})*invc ; col 0 = x0 ; inputs at t=512 are 0.
__global__ __launch_bounds__(128)
void stream_kernel(const float* __restrict__ xt, float* __restrict__ out) {
    int tid  = threadIdx.x;          // 0..127
    int b    = blockIdx.y;
    int j    = blockIdx.x * 128 + tid;
    bool obs = j < NOBS;             // uniform per block (blockIdx.x < 4)
    float d    = obs ? PP : QQ;
    float invc = obs ? (1.0f / 0.875f) : 1.0f;

    size_t cj = (size_t)b * NN + j;
    float c1v  = bf2f(g_c1[cj]);
    float c2av = bf2f(g_c2a[cj]),  c2bv = bf2f(g_c2b[cj]);
    float c3aav = bf2f(g_c3aa[cj]), c3abv = bf2f(g_c3ab[cj]);
    float c3bav = bf2f(g_c3ba[cj]), c3bbv = bf2f(g_c3bb[cj]);

    const float* tp = xt + ((size_t)b * NOBS + (obs ? j : 0)) * TT;  // (b,k,t): t-contiguous
    float z0j = obs ? tp[0] : 0.0f;

    float pw = 1.0f;
    float u1 = 0.f, u2 = 0.f;
    float y11 = 0.f, y12 = 0.f, y21 = 0.f, y22 = 0.f;
    float w1 = 0.f, w2a = 0.f, w2b = 0.f;
    float w3aa = 0.f, w3ab = 0.f, w3ba = 0.f, w3bb = 0.f;
    float sd = z0j;
    float r = 0.f, H = 0.f, G = 0.f;
    float zc = 0.f;

    const unsigned short* vp = g_VET + cj * TT;   // t-contiguous
    float* op = out + cj * TT;

#define ADVV(vev_, vv_) do {                                                \
        w3aa = d * w3aa + y11;  w3ab = d * w3ab + y12;                      \
        w3ba = d * w3ba + y21;  w3bb = d * w3bb + y22;                      \
        w2a  = d * w2a + u1;    w2b  = d * w2b + u2;                        \
        w1   = d * w1 + pw;                                                 \
        G    = d * G + H;                                                   \
        H    = PP * H + (vev_);                                             \
        r    = d * r + (vv_);                                               \
        sd   = d * sd;                                                      \
        y11  = PP * y11 + u1;   y12 = QQ * y12 + u1;                        \
        y21  = PP * y21 + u2;   y22 = QQ * y22 + u2;                        \
        u1   = PP * u1 + pw;    u2  = QQ * u2 + pw;                         \
        pw  *= PP;                                                          \
        zc = sd + w1 * c1v + w2a * c2av + w2b * c2bv                        \
           + w3aa * c3aav + w3ab * c3abv + w3ba * c3bav + w3bb * c3bbv      \
           + r + G;                                                         \
    } while (0)

#define CVV(i) ((unsigned short)((i) < 8 ? cv0[(i)] : cv1[(i) - 8]))
#define CTV(i) ((i) < 4 ? ct0[(i)] : (i) < 8 ? ct1[(i) - 4] : (i) < 12 ? ct2[(i) - 8] : ct3[(i) - 12])

    // current input block: t = [0..15]
    short8 cv0 = *(const short8*)(vp);
    short8 cv1 = *(const short8*)(vp + 8);
    f32x4 ct0 = {0,0,0,0}, ct1 = {0,0,0,0}, ct2 = {0,0,0,0}, ct3 = {0,0,0,0};
    if (obs) {
        ct0 = *(const f32x4*)(tp);      ct1 = *(const f32x4*)(tp + 4);
        ct2 = *(const f32x4*)(tp + 8);  ct3 = *(const f32x4*)(tp + 12);
    }

    float buf[16];

    // ---- m = 0 (tau 0..15; ADV t=1..16; tau 0 = x0) ----
    {
        short8 nv0 = *(const short8*)(vp + 16);
        short8 nv1 = *(const short8*)(vp + 24);
        f32x4 nt0 = {0,0,0,0}, nt1 = {0,0,0,0}, nt2 = {0,0,0,0}, nt3 = {0,0,0,0};
        if (obs) {
            nt0 = *(const f32x4*)(tp + 16); nt1 = *(const f32x4*)(tp + 20);
            nt2 = *(const f32x4*)(tp + 24); nt3 = *(const f32x4*)(tp + 28);
        }
        buf[0] = z0j;
#pragma unroll
        for (int i = 1; i <= 15; ++i) {
            float vev = bf2f(CVV(i));
            float vv  = obs ? BETA * CTV(i) : 0.f;
            ADVV(vev, vv);
            if (i >= 2) buf[i - 1] = (zc - vv) * invc;
        }
        {
            float vev = bf2f((unsigned short)nv0[0]);     // t = 16
            float vv  = obs ? BETA * nt0[0] : 0.f;
            ADVV(vev, vv);
            buf[15] = (zc - vv) * invc;
        }
        float4* o4 = (float4*)op;
        o4[0] = make_float4(buf[0], buf[1], buf[2], buf[3]);
        o4[1] = make_float4(buf[4], buf[5], buf[6], buf[7]);
        o4[2] = make_float4(buf[8], buf[9], buf[10], buf[11]);
        o4[3] = make_float4(buf[12], buf[13], buf[14], buf[15]);
        cv0 = nv0; cv1 = nv1; ct0 = nt0; ct1 = nt1; ct2 = nt2; ct3 = nt3;
    }

    // ---- m = 1..31 (tau tb..tb+15; ADV t=tb+1..tb+16) ----
    for (int m = 1; m < 32; ++m) {
        int tb = m * 16;
        short8 nv0 = {0,0,0,0,0,0,0,0}, nv1 = {0,0,0,0,0,0,0,0};
        f32x4 nt0 = {0,0,0,0}, nt1 = {0,0,0,0}, nt2 = {0,0,0,0}, nt3 = {0,0,0,0};
        if (m < 31) {
            nv0 = *(const short8*)(vp + tb + 16);
            nv1 = *(const short8*)(vp + tb + 24);
            if (obs) {
                nt0 = *(const f32x4*)(tp + tb + 16); nt1 = *(const f32x4*)(tp + tb + 20);
                nt2 = *(const f32x4*)(tp + tb + 24); nt3 = *(const f32x4*)(tp + tb + 28);
            }
        }
#pragma unroll
        for (int i = 1; i <= 15; ++i) {
            float vev = bf2f(CVV(i));
            float vv  = obs ? BETA * CTV(i) : 0.f;
            ADVV(vev, vv);
            buf[i - 1] = (zc - vv) * invc;
        }
        {
            float vev = bf2f((unsigned short)nv0[0]);     // t = tb+16 (m=31 -> zeros)
            float vv  = obs ? BETA * nt0[0] : 0.f;
            ADVV(vev, vv);
            buf[15] = (zc - vv) * invc;
        }
        float4* o4 = (float4*)(op + tb);
        o4[0] = make_float4(buf[0], buf[1], buf[2], buf[3]);
        o4[1] = make_float4(buf[4], buf[5], buf[6], buf[7]);
        o4[2] = make_float4(buf[8], buf[9], buf[10], buf[11]);
        o4[3] = make_float4(buf[12], buf[13], buf[14], buf[15]);
        cv0 = nv0; cv1 = nv1; ct0 = nt0; ct1 = nt1; ct2 = nt2; ct3 = nt3;
    }
#undef ADVV
#undef CVV
#undef CTV
}

extern "C" void kernel_launch(void* const* d_in, const int* in_sizes, int n_in,
                              void* d_out, int out_size, void* d_ws, size_t ws_size,
                              hipStream_t stream) {
    const float* xt = (const float*)d_in[0];   // (16, 512, 512)
    const float* w  = (const float*)d_in[1];   // (2048, 2048)
    float* out = (float*)d_out;                // (16, 2048, 512)

    hipLaunchKernelGGL(build_x_kernel, dim3(1024), dim3(256), 0, stream, w);
    hipLaunchKernelGGL(tch_transpose_kernel, dim3(NOBS / 32, TT / 32, NB), dim3(256), 0, stream, xt);
    hipLaunchKernelGGL(z0_init_kernel, dim3(32), dim3(256), 0, stream, xt);
    hipLaunchKernelGGL(gemm_small, dim3(NN / 16, 1, 1), dim3(256), 0, stream, 0);      // c1
    hipLaunchKernelGGL(gemm_vet, dim3(NN / 128, TT / 128, NB), dim3(256), 0, stream);  // VE^T
    hipLaunchKernelGGL(gemm_small, dim3(NN / 16, 1, 2), dim3(256), 0, stream, 1);      // c2a,c2b
    hipLaunchKernelGGL(gemm_small, dim3(NN / 16, 1, 4), dim3(256), 0, stream, 3);      // c3aa..c3bb
    hipLaunchKernelGGL(stream_kernel, dim3(NN / 128, NB), dim3(128), 0, stream, xt, out);
}